// Round 1
// baseline (1164.551 us; speedup 1.0000x reference)
//
#include <hip/hip_runtime.h>
#include <math.h>

// Problem constants (B,S,D,H fixed by the reference)
#define B_  2
#define S_  2048
#define D_  1024
#define H_  16
#define DH_ 64
#define M_  (B_ * S_)   // 4096 rows of the projection GEMMs

// ---------------------------------------------------------------------------
// Kernel 1: fused QKV projection.  C = x @ W + b, exact GELU when which==0.
// 64x64 output tile per block, BK=16, 256 threads, 4x4 register tile.
// LDS strides: As 20 (=16+4), Bs 68 (=64+4) -> all compute reads are aligned
// float4 with <=2-way bank conflicts (free on gfx950, m136).
// ---------------------------------------------------------------------------
__global__ __launch_bounds__(256) void qkv_gemm_kernel(
    const float* __restrict__ x,
    const float* __restrict__ Wq, const float* __restrict__ bq,
    const float* __restrict__ Wk, const float* __restrict__ bk,
    const float* __restrict__ Wv, const float* __restrict__ bv,
    float* __restrict__ Qo, float* __restrict__ Ko, float* __restrict__ Vo)
{
    const int which = blockIdx.z;
    const float* __restrict__ W    = (which == 0) ? Wq : (which == 1) ? Wk : Wv;
    const float* __restrict__ bias = (which == 0) ? bq : (which == 1) ? bk : bv;
    float* __restrict__ out        = (which == 0) ? Qo : (which == 1) ? Ko : Vo;

    const int m0  = blockIdx.y * 64;
    const int n0  = blockIdx.x * 64;
    const int tid = threadIdx.x;
    const int ty  = tid >> 4;        // 0..15
    const int tx  = tid & 15;        // 0..15

    __shared__ float As[64][20];     // [m][k], stride 20
    __shared__ float Bs[16][68];     // [k][n], stride 68

    float acc[4][4] = {};

    // Staging index maps (float4 granularity)
    const int ar  = tid >> 2;        // A: row 0..63
    const int ac4 = tid & 3;         // A: k-chunk 0..3
    const int br  = tid >> 4;        // B: k-row 0..15
    const int bc4 = tid & 15;        // B: n-chunk 0..15

    for (int k0 = 0; k0 < D_; k0 += 16) {
        const float4 av  = *(const float4*)(x + (size_t)(m0 + ar) * D_ + k0 + ac4 * 4);
        const float4 bvv = *(const float4*)(W + (size_t)(k0 + br) * D_ + n0 + bc4 * 4);
        __syncthreads();                       // previous tile fully consumed
        *(float4*)&As[ar][ac4 * 4] = av;
        *(float4*)&Bs[br][bc4 * 4] = bvv;
        __syncthreads();                       // staging visible

        #pragma unroll
        for (int kk = 0; kk < 16; kk += 4) {
            float4 a[4], b[4];
            #pragma unroll
            for (int i = 0; i < 4; ++i) a[i] = *(const float4*)&As[ty * 4 + i][kk];
            #pragma unroll
            for (int u = 0; u < 4; ++u) b[u] = *(const float4*)&Bs[kk + u][tx * 4];
            #pragma unroll
            for (int i = 0; i < 4; ++i) {
                const float ax[4] = {a[i].x, a[i].y, a[i].z, a[i].w};
                #pragma unroll
                for (int u = 0; u < 4; ++u) {
                    const float* bu = (const float*)&b[u];
                    #pragma unroll
                    for (int j = 0; j < 4; ++j) acc[i][j] += ax[u] * bu[j];
                }
            }
        }
    }

    // Epilogue: bias (+ exact GELU for Q), float4 store
    #pragma unroll
    for (int i = 0; i < 4; ++i) {
        const int row = m0 + ty * 4 + i;
        const int col = n0 + tx * 4;
        float4 v;
        float* vp = (float*)&v;
        #pragma unroll
        for (int j = 0; j < 4; ++j) {
            float t = acc[i][j] + bias[col + j];
            if (which == 0) t = 0.5f * t * (1.0f + erff(t * 0.70710678118654752f));
            vp[j] = t;
        }
        *(float4*)(out + (size_t)row * D_ + col) = v;
    }
}

// ---------------------------------------------------------------------------
// Kernel 2: flash-style attention (no scale, no mask — faithful to reference).
// One block = one (b,h) and 64 query rows.  256 threads as 16x16 (ty,tx).
//   QK phase:  q-rows 4ty+i, k-cols tx+16j  (Ks reads: aligned b128, 2-way)
//   softmax :  row reductions via __shfl_xor over the 16-lane tx group
//   PV phase:  out-dims 4tx+j               (Vs reads: aligned b128, 0-conflict)
// P round-trips through Ss; rows 4ty+i are written/read by the owning wave
// only, so no extra barrier is needed for Ss.
// LDS = 17408*3 + 16384 = 68.6 KB -> 2 blocks/CU.
// ---------------------------------------------------------------------------
__global__ __launch_bounds__(256) void attn_kernel(
    const float* __restrict__ Q, const float* __restrict__ K,
    const float* __restrict__ V, float* __restrict__ out)
{
    const int tid = threadIdx.x;
    const int ty  = tid >> 4;
    const int tx  = tid & 15;
    const int bh  = blockIdx.y;          // 0..31
    const int b   = bh >> 4;
    const int h   = bh & 15;
    const int q0  = blockIdx.x * 64;

    const float* __restrict__ Qb = Q + (size_t)b * S_ * D_ + h * DH_;
    const float* __restrict__ Kb = K + (size_t)b * S_ * D_ + h * DH_;
    const float* __restrict__ Vb = V + (size_t)b * S_ * D_ + h * DH_;

    __shared__ float Qs[64][68];
    __shared__ float Ks[64][68];
    __shared__ float Vs[64][64];
    __shared__ float Ss[64][68];

    // Load Q tile once (64 rows x 64 dims)
    #pragma unroll
    for (int li = 0; li < 4; ++li) {
        const int idx = tid + li * 256;
        const int r = idx >> 4, c4 = idx & 15;
        *(float4*)&Qs[r][c4 * 4] =
            *(const float4*)(Qb + (size_t)(q0 + r) * D_ + c4 * 4);
    }

    float O[4][4] = {};
    float m_i[4], l_i[4];
    #pragma unroll
    for (int i = 0; i < 4; ++i) { m_i[i] = -INFINITY; l_i[i] = 0.0f; }

    for (int k0 = 0; k0 < S_; k0 += 64) {
        // ---- stage K,V tile: global -> regs -> (barrier) -> LDS ----
        float4 kreg[2], vreg[2];
        #pragma unroll
        for (int li = 0; li < 2; ++li) {
            const int idx = tid + li * 256;
            const int r = idx >> 3, c4 = idx & 7;   // 64 rows x 8 chunks... (see below)
            (void)r; (void)c4;
        }
        // 64 rows x 16 float4-chunks = 1024 chunks; 256 threads x 4
        float4 kr[2], vr[2];
        #pragma unroll
        for (int li = 0; li < 2; ++li) {
            const int idx = tid + li * 256;
            const int r = idx >> 4, c4 = idx & 15;
            kr[li] = *(const float4*)(Kb + (size_t)(k0 + r) * D_ + c4 * 4);
            vr[li] = *(const float4*)(Vb + (size_t)(k0 + r) * D_ + c4 * 4);
        }
        float4 kr2[2], vr2[2];
        #pragma unroll
        for (int li = 0; li < 2; ++li) {
            const int idx = tid + (li + 2) * 256;
            const int r = idx >> 4, c4 = idx & 15;
            kr2[li] = *(const float4*)(Kb + (size_t)(k0 + r) * D_ + c4 * 4);
            vr2[li] = *(const float4*)(Vb + (size_t)(k0 + r) * D_ + c4 * 4);
        }
        (void)kreg; (void)vreg;
        __syncthreads();                 // everyone done reading prev Ks/Vs
        #pragma unroll
        for (int li = 0; li < 2; ++li) {
            const int idx = tid + li * 256;
            const int r = idx >> 4, c4 = idx & 15;
            *(float4*)&Ks[r][c4 * 4] = kr[li];
            *(float4*)&Vs[r][c4 * 4] = vr[li];
        }
        #pragma unroll
        for (int li = 0; li < 2; ++li) {
            const int idx = tid + (li + 2) * 256;
            const int r = idx >> 4, c4 = idx & 15;
            *(float4*)&Ks[r][c4 * 4] = kr2[li];
            *(float4*)&Vs[r][c4 * 4] = vr2[li];
        }
        __syncthreads();                 // staging visible

        // ---- QK^T: s[i][j] = q(4ty+i) . k(tx+16j) ----
        float s[4][4] = {};
        #pragma unroll
        for (int d = 0; d < DH_; d += 4) {
            float4 qv[4], kv[4];
            #pragma unroll
            for (int i = 0; i < 4; ++i) qv[i] = *(const float4*)&Qs[4 * ty + i][d];
            #pragma unroll
            for (int j = 0; j < 4; ++j) kv[j] = *(const float4*)&Ks[tx + 16 * j][d];
            #pragma unroll
            for (int i = 0; i < 4; ++i)
                #pragma unroll
                for (int j = 0; j < 4; ++j)
                    s[i][j] += qv[i].x * kv[j].x + qv[i].y * kv[j].y +
                               qv[i].z * kv[j].z + qv[i].w * kv[j].w;
        }

        // ---- online softmax update (per q-row, across the 16-lane tx group) ----
        #pragma unroll
        for (int i = 0; i < 4; ++i) {
            float tmax = fmaxf(fmaxf(s[i][0], s[i][1]), fmaxf(s[i][2], s[i][3]));
            #pragma unroll
            for (int off = 1; off < 16; off <<= 1)
                tmax = fmaxf(tmax, __shfl_xor(tmax, off, 64));
            const float mnew  = fmaxf(m_i[i], tmax);
            const float alpha = __expf(m_i[i] - mnew);
            float rsum = 0.0f;
            float p[4];
            #pragma unroll
            for (int j = 0; j < 4; ++j) {
                p[j] = __expf(s[i][j] - mnew);
                rsum += p[j];
            }
            #pragma unroll
            for (int off = 1; off < 16; off <<= 1)
                rsum += __shfl_xor(rsum, off, 64);
            l_i[i] = l_i[i] * alpha + rsum;
            m_i[i] = mnew;
            #pragma unroll
            for (int j = 0; j < 4; ++j) {
                O[i][j] *= alpha;
                Ss[4 * ty + i][tx + 16 * j] = p[j];   // wave-local region
            }
        }

        // ---- PV: O[i][j] += sum_kc P(4ty+i,kc) * V(kc, 4tx+j) ----
        #pragma unroll
        for (int kc = 0; kc < 64; kc += 4) {
            float4 Sv[4], Vv[4];
            #pragma unroll
            for (int i = 0; i < 4; ++i) Sv[i] = *(const float4*)&Ss[4 * ty + i][kc];
            #pragma unroll
            for (int u = 0; u < 4; ++u) Vv[u] = *(const float4*)&Vs[kc + u][4 * tx];
            #pragma unroll
            for (int i = 0; i < 4; ++i) {
                const float sx[4] = {Sv[i].x, Sv[i].y, Sv[i].z, Sv[i].w};
                #pragma unroll
                for (int u = 0; u < 4; ++u) {
                    const float* vu = (const float*)&Vv[u];
                    #pragma unroll
                    for (int j = 0; j < 4; ++j) O[i][j] += sx[u] * vu[j];
                }
            }
        }
    }

    // ---- epilogue: normalize and store ----
    #pragma unroll
    for (int i = 0; i < 4; ++i) {
        const float inv_l = 1.0f / l_i[i];
        const int row = q0 + 4 * ty + i;
        float4 v;
        float* vp = (float*)&v;
        #pragma unroll
        for (int j = 0; j < 4; ++j) vp[j] = O[i][j] * inv_l;
        *(float4*)(out + ((size_t)b * S_ + row) * D_ + h * DH_ + 4 * tx) = v;
    }
}

// ---------------------------------------------------------------------------
extern "C" void kernel_launch(void* const* d_in, const int* in_sizes, int n_in,
                              void* d_out, int out_size, void* d_ws, size_t ws_size,
                              hipStream_t stream) {
    const float* x  = (const float*)d_in[0];
    const float* Wq = (const float*)d_in[1];
    const float* bq = (const float*)d_in[2];
    const float* Wk = (const float*)d_in[3];
    const float* bk = (const float*)d_in[4];
    const float* Wv = (const float*)d_in[5];
    const float* bv = (const float*)d_in[6];
    float* out = (float*)d_out;

    const size_t n_elem = (size_t)M_ * D_;    // 4096*1024 floats per matrix
    float* Qw = (float*)d_ws;
    float* Kw = Qw + n_elem;
    float* Vw = Kw + n_elem;

    dim3 g1(D_ / 64, M_ / 64, 3);             // 16 x 64 x 3
    qkv_gemm_kernel<<<g1, 256, 0, stream>>>(x, Wq, bq, Wk, bk, Wv, bv, Qw, Kw, Vw);

    dim3 g2(S_ / 64, B_ * H_);                // 32 x 32
    attn_kernel<<<g2, 256, 0, stream>>>(Qw, Kw, Vw, out);
}

// Round 2
// 401.803 us; speedup vs baseline: 2.8983x; 2.8983x over previous
//
#include <hip/hip_runtime.h>
#include <math.h>

#define B_  2
#define S_  2048
#define D_  1024
#define H_  16
#define DH_ 64
#define M_  (B_ * S_)   // 4096

typedef _Float16 half_t;
typedef __attribute__((ext_vector_type(8))) _Float16 h8;
typedef __attribute__((ext_vector_type(4))) _Float16 h4;
typedef __attribute__((ext_vector_type(4))) float   f32x4;

// ---------------------------------------------------------------------------
// Kernel 1: fused QKV projection with fp16 MFMA.
// C = x @ W + b (exact GELU when which==0), output stored as fp16 to ws.
// 128x128 tile, BK=32, 256 threads = 4 waves (2x2), each wave 64x64 via
// 4x4 grid of 16x16x32 MFMA.  fp32->fp16 conversion happens during staging.
// LDS strides 40 halves (80 B): A-frag/B-frag b128 reads are 2-way -> free.
// ---------------------------------------------------------------------------
__global__ __launch_bounds__(256) void qkv_gemm_f16(
    const float* __restrict__ x,
    const float* __restrict__ Wq, const float* __restrict__ bq,
    const float* __restrict__ Wk, const float* __restrict__ bk,
    const float* __restrict__ Wv, const float* __restrict__ bv,
    half_t* __restrict__ Qo, half_t* __restrict__ Ko, half_t* __restrict__ Vo)
{
    const int which = blockIdx.z;
    const float* __restrict__ W    = (which == 0) ? Wq : (which == 1) ? Wk : Wv;
    const float* __restrict__ bias = (which == 0) ? bq : (which == 1) ? bk : bv;
    half_t* __restrict__ out       = (which == 0) ? Qo : (which == 1) ? Ko : Vo;

    const int n0   = blockIdx.x * 128;
    const int m0   = blockIdx.y * 128;
    const int tid  = threadIdx.x;
    const int lane = tid & 63;
    const int wave = tid >> 6;
    const int wm   = (wave >> 1) * 64;   // wave row offset in tile
    const int wn   = (wave & 1) * 64;    // wave col offset in tile
    const int ln   = lane & 15;
    const int quad = lane >> 4;

    __shared__ __align__(16) half_t As[128][40];   // [m][k]
    __shared__ __align__(16) half_t Bs[128][40];   // transposed: [n][k]

    f32x4 acc[4][4];
    #pragma unroll
    for (int i = 0; i < 4; ++i)
        #pragma unroll
        for (int j = 0; j < 4; ++j) acc[i][j] = (f32x4){0.f, 0.f, 0.f, 0.f};

    for (int k0 = 0; k0 < D_; k0 += 32) {
        // ---- global loads (fp32) ----
        float4 av[4], bv4[4];
        #pragma unroll
        for (int l = 0; l < 4; ++l) {
            const int c  = tid + l * 256;
            const int ar = c >> 3, ak4 = c & 7;          // 128 rows x 8 chunks
            av[l] = *(const float4*)(x + (size_t)(m0 + ar) * D_ + k0 + ak4 * 4);
            const int bk = c >> 5, bn4 = c & 31;         // 32 k-rows x 32 chunks
            bv4[l] = *(const float4*)(W + (size_t)(k0 + bk) * D_ + n0 + bn4 * 4);
        }
        __syncthreads();   // previous tile consumed
        #pragma unroll
        for (int l = 0; l < 4; ++l) {
            const int c  = tid + l * 256;
            const int ar = c >> 3, ak4 = c & 7;
            h4 a; a[0] = (half_t)av[l].x; a[1] = (half_t)av[l].y;
                  a[2] = (half_t)av[l].z; a[3] = (half_t)av[l].w;
            *(h4*)&As[ar][ak4 * 4] = a;
            const int bk = c >> 5, bn4 = c & 31;
            Bs[bn4 * 4 + 0][bk] = (half_t)bv4[l].x;
            Bs[bn4 * 4 + 1][bk] = (half_t)bv4[l].y;
            Bs[bn4 * 4 + 2][bk] = (half_t)bv4[l].z;
            Bs[bn4 * 4 + 3][bk] = (half_t)bv4[l].w;
        }
        __syncthreads();   // staging visible

        // ---- MFMA: A[m=ln][k=quad*8+j], B[k=quad*8+j][n=ln] from BsT[n][k] ----
        h8 af[4], bf[4];
        #pragma unroll
        for (int i = 0; i < 4; ++i) af[i] = *(const h8*)&As[wm + i * 16 + ln][quad * 8];
        #pragma unroll
        for (int j = 0; j < 4; ++j) bf[j] = *(const h8*)&Bs[wn + j * 16 + ln][quad * 8];
        #pragma unroll
        for (int i = 0; i < 4; ++i)
            #pragma unroll
            for (int j = 0; j < 4; ++j)
                acc[i][j] = __builtin_amdgcn_mfma_f32_16x16x32_f16(af[i], bf[j], acc[i][j], 0, 0, 0);
    }

    // ---- epilogue: bias (+ exact GELU for Q), store fp16 ----
    // C/D layout: col = ln, row = quad*4 + reg  (m89-verified)
    #pragma unroll
    for (int j = 0; j < 4; ++j) {
        const int col = n0 + wn + j * 16 + ln;
        const float bb = bias[col];
        #pragma unroll
        for (int i = 0; i < 4; ++i) {
            #pragma unroll
            for (int r = 0; r < 4; ++r) {
                const int row = m0 + wm + i * 16 + quad * 4 + r;
                float t = acc[i][j][r] + bb;
                if (which == 0) t = 0.5f * t * (1.0f + erff(t * 0.70710678118654752f));
                out[(size_t)row * D_ + col] = (half_t)t;
            }
        }
    }
}

// ---------------------------------------------------------------------------
// Kernel 2: flash attention with fp16 MFMA (no scale, no mask — faithful).
// Block = (b,h) x 64 q-rows; 4 waves, each owns 16 q-rows.
// QK^T: A = Q rows (natural layout), B = K^T -> reads K natural layout.
// PV:   A = P (LDS round-trip, wave-local rows), B = V^T -> Vt transposed.
// All MFMA frag reads are aligned b128 with <=2-way bank conflicts.
// LDS = 4 * 64*72*2 = 36.9 KB -> 4 blocks/CU.
// ---------------------------------------------------------------------------
__global__ __launch_bounds__(256) void attn_f16(
    const half_t* __restrict__ Q, const half_t* __restrict__ K,
    const half_t* __restrict__ V, float* __restrict__ out)
{
    const int tid  = threadIdx.x;
    const int lane = tid & 63;
    const int wave = tid >> 6;
    const int ln   = lane & 15;
    const int quad = lane >> 4;
    const int bh   = blockIdx.y;
    const int b    = bh >> 4;
    const int h    = bh & 15;
    const int q0   = blockIdx.x * 64;

    const half_t* __restrict__ Qb = Q + (size_t)b * S_ * D_ + h * DH_;
    const half_t* __restrict__ Kb = K + (size_t)b * S_ * D_ + h * DH_;
    const half_t* __restrict__ Vb = V + (size_t)b * S_ * D_ + h * DH_;

    __shared__ __align__(16) half_t Qs[64][72];
    __shared__ __align__(16) half_t Ks[64][72];
    __shared__ __align__(16) half_t Vt[64][72];   // [dim][key]
    __shared__ __align__(16) half_t Ps[64][72];   // wave-local 16-row bands

    // ---- load Q tile (64 x 64 halves = 512 h8-chunks, 2/thread) ----
    #pragma unroll
    for (int l = 0; l < 2; ++l) {
        const int c = tid + l * 256;
        const int r = c >> 3, k8 = c & 7;
        *(h8*)&Qs[r][k8 * 8] = *(const h8*)(Qb + (size_t)(q0 + r) * D_ + k8 * 8);
    }

    f32x4 O[4];
    #pragma unroll
    for (int j = 0; j < 4; ++j) O[j] = (f32x4){0.f, 0.f, 0.f, 0.f};
    float m_i[4], l_i[4];
    #pragma unroll
    for (int r = 0; r < 4; ++r) { m_i[r] = -INFINITY; l_i[r] = 0.0f; }

    for (int k0 = 0; k0 < S_; k0 += 64) {
        // ---- stage K (natural) and V (transposed) ----
        h8 kr[2];
        #pragma unroll
        for (int l = 0; l < 2; ++l) {
            const int c = tid + l * 256;
            const int r = c >> 3, k8 = c & 7;
            kr[l] = *(const h8*)(Kb + (size_t)(k0 + r) * D_ + k8 * 8);
        }
        h4 vr[4];
        #pragma unroll
        for (int l = 0; l < 4; ++l) {
            const int c = tid + l * 256;
            const int key = c >> 4, d4 = c & 15;
            vr[l] = *(const h4*)(Vb + (size_t)(k0 + key) * D_ + d4 * 4);
        }
        __syncthreads();   // previous tile consumed
        #pragma unroll
        for (int l = 0; l < 2; ++l) {
            const int c = tid + l * 256;
            const int r = c >> 3, k8 = c & 7;
            *(h8*)&Ks[r][k8 * 8] = kr[l];
        }
        #pragma unroll
        for (int l = 0; l < 4; ++l) {
            const int c = tid + l * 256;
            const int key = c >> 4, d4 = c & 15;
            Vt[d4 * 4 + 0][key] = vr[l][0];
            Vt[d4 * 4 + 1][key] = vr[l][1];
            Vt[d4 * 4 + 2][key] = vr[l][2];
            Vt[d4 * 4 + 3][key] = vr[l][3];
        }
        __syncthreads();   // staging (and first-iter Q) visible

        // ---- S = Q K^T : per wave 16 q-rows x 64 keys ----
        const h8 a0 = *(const h8*)&Qs[wave * 16 + ln][quad * 8];
        const h8 a1 = *(const h8*)&Qs[wave * 16 + ln][32 + quad * 8];
        f32x4 s[4];
        #pragma unroll
        for (int j = 0; j < 4; ++j) {
            const h8 b0 = *(const h8*)&Ks[j * 16 + ln][quad * 8];
            const h8 b1 = *(const h8*)&Ks[j * 16 + ln][32 + quad * 8];
            f32x4 t = (f32x4){0.f, 0.f, 0.f, 0.f};
            t = __builtin_amdgcn_mfma_f32_16x16x32_f16(a0, b0, t, 0, 0, 0);
            t = __builtin_amdgcn_mfma_f32_16x16x32_f16(a1, b1, t, 0, 0, 0);
            s[j] = t;
        }

        // ---- online softmax (rows quad*4+r, reduce over 16-lane col group) ----
        #pragma unroll
        for (int r = 0; r < 4; ++r) {
            float sm = fmaxf(fmaxf(s[0][r], s[1][r]), fmaxf(s[2][r], s[3][r]));
            #pragma unroll
            for (int off = 1; off < 16; off <<= 1)
                sm = fmaxf(sm, __shfl_xor(sm, off, 64));
            const float mnew  = fmaxf(m_i[r], sm);
            const float alpha = __expf(m_i[r] - mnew);
            float p[4], rsum = 0.0f;
            #pragma unroll
            for (int j = 0; j < 4; ++j) { p[j] = __expf(s[j][r] - mnew); rsum += p[j]; }
            #pragma unroll
            for (int off = 1; off < 16; off <<= 1)
                rsum += __shfl_xor(rsum, off, 64);
            l_i[r] = l_i[r] * alpha + rsum;
            m_i[r] = mnew;
            #pragma unroll
            for (int j = 0; j < 4; ++j) {
                O[j][r] *= alpha;
                Ps[wave * 16 + quad * 4 + r][j * 16 + ln] = (half_t)p[j];
            }
        }

        // ---- O += P V : A = P (wave-local LDS band), B = V^T from Vt ----
        const h8 pa0 = *(const h8*)&Ps[wave * 16 + ln][quad * 8];
        const h8 pa1 = *(const h8*)&Ps[wave * 16 + ln][32 + quad * 8];
        #pragma unroll
        for (int j = 0; j < 4; ++j) {
            const h8 vb0 = *(const h8*)&Vt[j * 16 + ln][quad * 8];
            const h8 vb1 = *(const h8*)&Vt[j * 16 + ln][32 + quad * 8];
            O[j] = __builtin_amdgcn_mfma_f32_16x16x32_f16(pa0, vb0, O[j], 0, 0, 0);
            O[j] = __builtin_amdgcn_mfma_f32_16x16x32_f16(pa1, vb1, O[j], 0, 0, 0);
        }
    }

    // ---- epilogue: normalize, store fp32 ----
    #pragma unroll
    for (int r = 0; r < 4; ++r) {
        const float inv = 1.0f / l_i[r];
        const int row = q0 + wave * 16 + quad * 4 + r;
        #pragma unroll
        for (int j = 0; j < 4; ++j)
            out[((size_t)b * S_ + row) * D_ + h * DH_ + j * 16 + ln] = O[j][r] * inv;
    }
}

// ---------------------------------------------------------------------------
extern "C" void kernel_launch(void* const* d_in, const int* in_sizes, int n_in,
                              void* d_out, int out_size, void* d_ws, size_t ws_size,
                              hipStream_t stream) {
    const float* x  = (const float*)d_in[0];
    const float* Wq = (const float*)d_in[1];
    const float* bq = (const float*)d_in[2];
    const float* Wk = (const float*)d_in[3];
    const float* bk = (const float*)d_in[4];
    const float* Wv = (const float*)d_in[5];
    const float* bv = (const float*)d_in[6];
    float* out = (float*)d_out;

    const size_t n_elem = (size_t)M_ * D_;
    half_t* Qh = (half_t*)d_ws;
    half_t* Kh = Qh + n_elem;
    half_t* Vh = Kh + n_elem;

    dim3 g1(D_ / 128, M_ / 128, 3);            // 8 x 32 x 3
    qkv_gemm_f16<<<g1, 256, 0, stream>>>(x, Wq, bq, Wk, bk, Wv, bv, Qh, Kh, Vh);

    dim3 g2(S_ / 64, B_ * H_);                 // 32 x 32
    attn_f16<<<g2, 256, 0, stream>>>(Qh, Kh, Vh, out);
}

// Round 3
// 231.865 us; speedup vs baseline: 5.0225x; 1.7329x over previous
//
#include <hip/hip_runtime.h>
#include <math.h>

#define B_  2
#define S_  2048
#define D_  1024
#define H_  16
#define DH_ 64
#define M_  (B_ * S_)   // 4096

typedef _Float16 half_t;
typedef __attribute__((ext_vector_type(8))) _Float16 h8;
typedef __attribute__((ext_vector_type(4))) float   f32x4;

// ---------------------------------------------------------------------------
// Prepass A: x fp32 -> fp16 (elementwise, h8 per thread)
// ---------------------------------------------------------------------------
__global__ __launch_bounds__(256) void convert_x_k(
    const float* __restrict__ x, half_t* __restrict__ xh)
{
    const size_t i = ((size_t)blockIdx.x * 256 + threadIdx.x) * 8;
    const float4 a = *(const float4*)(x + i);
    const float4 b = *(const float4*)(x + i + 4);
    h8 o;
    o[0] = (half_t)a.x; o[1] = (half_t)a.y; o[2] = (half_t)a.z; o[3] = (half_t)a.w;
    o[4] = (half_t)b.x; o[5] = (half_t)b.y; o[6] = (half_t)b.z; o[7] = (half_t)b.w;
    *(h8*)(xh + i) = o;
}

// ---------------------------------------------------------------------------
// Prepass B: W [k][n] fp32 -> Wt [n][k] fp16 (3 matrices, blockIdx.y)
// Per wave: lane = n offset; 8 coalesced 256B row reads, one scattered h8 write.
// ---------------------------------------------------------------------------
__global__ __launch_bounds__(256) void transW_k(
    const float* __restrict__ Wq, const float* __restrict__ Wk,
    const float* __restrict__ Wv, half_t* __restrict__ Wt)
{
    const int which = blockIdx.y;
    const float* __restrict__ W = (which == 0) ? Wq : (which == 1) ? Wk : Wv;
    half_t* __restrict__ T = Wt + (size_t)which * D_ * D_;
    const int gw   = blockIdx.x * 4 + (threadIdx.x >> 6);   // 0..2047
    const int lane = threadIdx.x & 63;
    const int n    = (gw & 15) * 64 + lane;
    const int k0   = (gw >> 4) * 8;
    h8 o;
    #pragma unroll
    for (int t = 0; t < 8; ++t) o[t] = (half_t)W[(size_t)(k0 + t) * D_ + n];
    *(h8*)(T + (size_t)n * D_ + k0) = o;
}

// ---------------------------------------------------------------------------
// Prepass C (after GEMM): V [b][s][h*64+d] fp16 -> Vt [bh][d][s] fp16
// lane = d; 8 coalesced 128B reads (consecutive d), one scattered h8 write.
// ---------------------------------------------------------------------------
__global__ __launch_bounds__(256) void transV_k(
    const half_t* __restrict__ V, half_t* __restrict__ Vt)
{
    const int gw   = blockIdx.x * 4 + (threadIdx.x >> 6);   // 0..8191
    const int lane = threadIdx.x & 63;                      // d
    const int bh   = gw >> 8;
    const int s0   = (gw & 255) * 8;
    const int b    = bh >> 4, h = bh & 15;
    h8 o;
    #pragma unroll
    for (int t = 0; t < 8; ++t)
        o[t] = V[((size_t)b * S_ + s0 + t) * D_ + h * DH_ + lane];
    *(h8*)(Vt + ((size_t)bh * DH_ + lane) * S_ + s0) = o;
}

// ---------------------------------------------------------------------------
// Kernel 1: QKV projection, fp16 MFMA, m93-style.
// Both operands k-minor in global -> pure h8 staging, no transposes in LDS.
// 128x128 tile, BK=64, 4 waves (2x2), 32 MFMA per wave per k-step.
// LDS stride 72 halves (36 dwords): b128 frag reads have even 8-phase bank
// coverage (start bank = 4*((row+quad) mod 8)) -> conflict-free minimum.
// ---------------------------------------------------------------------------
__global__ __launch_bounds__(256) void qkv_gemm_f16(
    const half_t* __restrict__ xh, const half_t* __restrict__ Wt,
    const float* __restrict__ bq, const float* __restrict__ bk,
    const float* __restrict__ bv,
    half_t* __restrict__ Qo, half_t* __restrict__ Ko, half_t* __restrict__ Vo)
{
    const int which = blockIdx.z;
    const half_t* __restrict__ Wp  = Wt + (size_t)which * D_ * D_;
    const float* __restrict__ bias = (which == 0) ? bq : (which == 1) ? bk : bv;
    half_t* __restrict__ out       = (which == 0) ? Qo : (which == 1) ? Ko : Vo;

    const int n0 = blockIdx.x * 128, m0 = blockIdx.y * 128;
    const int tid = threadIdx.x, lane = tid & 63, wave = tid >> 6;
    const int wm = (wave >> 1) * 64, wn = (wave & 1) * 64;
    const int ln = lane & 15, quad = lane >> 4;

    __shared__ __align__(16) half_t As[128][72];
    __shared__ __align__(16) half_t Bs[128][72];

    f32x4 acc[4][4];
    #pragma unroll
    for (int i = 0; i < 4; ++i)
        #pragma unroll
        for (int j = 0; j < 4; ++j) acc[i][j] = (f32x4){0.f, 0.f, 0.f, 0.f};

    for (int k0 = 0; k0 < D_; k0 += 64) {
        h8 ar[4], br[4];
        #pragma unroll
        for (int l = 0; l < 4; ++l) {
            const int c = tid + l * 256;
            const int r = c >> 3, k8 = c & 7;
            ar[l] = *(const h8*)(xh + (size_t)(m0 + r) * D_ + k0 + k8 * 8);
            br[l] = *(const h8*)(Wp + (size_t)(n0 + r) * D_ + k0 + k8 * 8);
        }
        __syncthreads();
        #pragma unroll
        for (int l = 0; l < 4; ++l) {
            const int c = tid + l * 256;
            const int r = c >> 3, k8 = c & 7;
            *(h8*)&As[r][k8 * 8] = ar[l];
            *(h8*)&Bs[r][k8 * 8] = br[l];
        }
        __syncthreads();

        #pragma unroll
        for (int kc = 0; kc < 2; ++kc) {
            h8 af[4], bf[4];
            #pragma unroll
            for (int i = 0; i < 4; ++i)
                af[i] = *(const h8*)&As[wm + i * 16 + ln][kc * 32 + quad * 8];
            #pragma unroll
            for (int j = 0; j < 4; ++j)
                bf[j] = *(const h8*)&Bs[wn + j * 16 + ln][kc * 32 + quad * 8];
            #pragma unroll
            for (int i = 0; i < 4; ++i)
                #pragma unroll
                for (int j = 0; j < 4; ++j)
                    acc[i][j] = __builtin_amdgcn_mfma_f32_16x16x32_f16(
                        af[i], bf[j], acc[i][j], 0, 0, 0);
        }
    }

    // Epilogue: bias (+ exact GELU for Q), fp16 natural [m][n] store.
    // C/D layout: col = ln, row = quad*4 + reg (m89-verified).
    #pragma unroll
    for (int j = 0; j < 4; ++j) {
        const int col = n0 + wn + j * 16 + ln;
        const float bb = bias[col];
        #pragma unroll
        for (int i = 0; i < 4; ++i) {
            #pragma unroll
            for (int r = 0; r < 4; ++r) {
                const int row = m0 + wm + i * 16 + quad * 4 + r;
                float t = acc[i][j][r] + bb;
                if (which == 0) t = 0.5f * t * (1.0f + erff(t * 0.70710678118654752f));
                out[(size_t)row * D_ + col] = (half_t)t;
            }
        }
    }
}

// ---------------------------------------------------------------------------
// Kernel 2: flash attention, fp16 MFMA (no scale/mask — faithful).
// Block = (b,h) x 64 q-rows; 4 waves x 16 q-rows.
// Q-fragments hoisted out of the k-loop.  V staged from pre-transposed Vt
// (natural h8 rows -> conflict-free).  Row-sum l computed by MFMA with a
// constant all-ones B fragment: D[m][n] = sum_k P[m][k] in every column, so
// each lane holds l for its own rows — no sum shuffles, no end broadcast.
// LDS = 4 * 64*72*2 = 36.9 KB.
// ---------------------------------------------------------------------------
__global__ __launch_bounds__(256) void attn_f16(
    const half_t* __restrict__ Q, const half_t* __restrict__ K,
    const half_t* __restrict__ Vt, float* __restrict__ out)
{
    const int tid  = threadIdx.x;
    const int lane = tid & 63;
    const int wave = tid >> 6;
    const int ln   = lane & 15;
    const int quad = lane >> 4;
    const int bh   = blockIdx.y;
    const int b    = bh >> 4;
    const int h    = bh & 15;
    const int q0   = blockIdx.x * 64;

    const half_t* __restrict__ Qb  = Q  + (size_t)b * S_ * D_ + h * DH_;
    const half_t* __restrict__ Kb  = K  + (size_t)b * S_ * D_ + h * DH_;
    const half_t* __restrict__ Vtb = Vt + (size_t)bh * DH_ * S_;

    __shared__ __align__(16) half_t Qs[64][72];
    __shared__ __align__(16) half_t Ks[64][72];   // [key][dim]
    __shared__ __align__(16) half_t Vs[64][72];   // [dim][key]
    __shared__ __align__(16) half_t Ps[64][72];   // wave-local 16-row bands

    // ---- load Q tile, then hoist Q fragments for the whole k-loop ----
    #pragma unroll
    for (int l = 0; l < 2; ++l) {
        const int c = tid + l * 256;
        const int r = c >> 3, k8 = c & 7;
        *(h8*)&Qs[r][k8 * 8] = *(const h8*)(Qb + (size_t)(q0 + r) * D_ + k8 * 8);
    }
    __syncthreads();
    const h8 a0 = *(const h8*)&Qs[wave * 16 + ln][quad * 8];
    const h8 a1 = *(const h8*)&Qs[wave * 16 + ln][32 + quad * 8];

    h8 ones8;
    #pragma unroll
    for (int t = 0; t < 8; ++t) ones8[t] = (half_t)1.0f;

    f32x4 O[4];
    #pragma unroll
    for (int j = 0; j < 4; ++j) O[j] = (f32x4){0.f, 0.f, 0.f, 0.f};
    f32x4 l5 = (f32x4){0.f, 0.f, 0.f, 0.f};
    float m_i[4];
    #pragma unroll
    for (int r = 0; r < 4; ++r) m_i[r] = -INFINITY;

    for (int k0 = 0; k0 < S_; k0 += 64) {
        // ---- stage K [key][dim] and V [dim][key] (both natural h8 rows) ----
        h8 kr[2], vr[2];
        #pragma unroll
        for (int l = 0; l < 2; ++l) {
            const int c = tid + l * 256;
            const int r = c >> 3, k8 = c & 7;
            kr[l] = *(const h8*)(Kb  + (size_t)(k0 + r) * D_ + k8 * 8);
            vr[l] = *(const h8*)(Vtb + (size_t)r * S_ + k0 + k8 * 8);
        }
        __syncthreads();   // previous tile fully consumed
        #pragma unroll
        for (int l = 0; l < 2; ++l) {
            const int c = tid + l * 256;
            const int r = c >> 3, k8 = c & 7;
            *(h8*)&Ks[r][k8 * 8] = kr[l];
            *(h8*)&Vs[r][k8 * 8] = vr[l];
        }
        __syncthreads();   // staging visible

        // ---- S = Q K^T : 16 q-rows x 64 keys per wave ----
        f32x4 s[4];
        #pragma unroll
        for (int j = 0; j < 4; ++j) {
            const h8 b0 = *(const h8*)&Ks[j * 16 + ln][quad * 8];
            const h8 b1 = *(const h8*)&Ks[j * 16 + ln][32 + quad * 8];
            f32x4 t = (f32x4){0.f, 0.f, 0.f, 0.f};
            t = __builtin_amdgcn_mfma_f32_16x16x32_f16(a0, b0, t, 0, 0, 0);
            t = __builtin_amdgcn_mfma_f32_16x16x32_f16(a1, b1, t, 0, 0, 0);
            s[j] = t;
        }

        // ---- online softmax: max via 4 shuffles; l handled by MFMA below ----
        #pragma unroll
        for (int r = 0; r < 4; ++r) {
            float sm = fmaxf(fmaxf(s[0][r], s[1][r]), fmaxf(s[2][r], s[3][r]));
            #pragma unroll
            for (int off = 1; off < 16; off <<= 1)
                sm = fmaxf(sm, __shfl_xor(sm, off, 64));
            const float mnew  = fmaxf(m_i[r], sm);
            const float alpha = __expf(m_i[r] - mnew);
            m_i[r] = mnew;
            l5[r] *= alpha;
            #pragma unroll
            for (int j = 0; j < 4; ++j) {
                O[j][r] *= alpha;
                Ps[wave * 16 + quad * 4 + r][j * 16 + ln] =
                    (half_t)__expf(s[j][r] - mnew);
            }
        }

        // ---- O += P V  (and l += P·1 via constant ones fragment) ----
        const h8 pa0 = *(const h8*)&Ps[wave * 16 + ln][quad * 8];
        const h8 pa1 = *(const h8*)&Ps[wave * 16 + ln][32 + quad * 8];
        #pragma unroll
        for (int j = 0; j < 4; ++j) {
            const h8 vb0 = *(const h8*)&Vs[j * 16 + ln][quad * 8];
            const h8 vb1 = *(const h8*)&Vs[j * 16 + ln][32 + quad * 8];
            O[j] = __builtin_amdgcn_mfma_f32_16x16x32_f16(pa0, vb0, O[j], 0, 0, 0);
            O[j] = __builtin_amdgcn_mfma_f32_16x16x32_f16(pa1, vb1, O[j], 0, 0, 0);
        }
        l5 = __builtin_amdgcn_mfma_f32_16x16x32_f16(pa0, ones8, l5, 0, 0, 0);
        l5 = __builtin_amdgcn_mfma_f32_16x16x32_f16(pa1, ones8, l5, 0, 0, 0);
    }

    // ---- epilogue: normalize, store fp32 ----
    #pragma unroll
    for (int r = 0; r < 4; ++r) {
        const float inv = 1.0f / l5[r];
        const int row = q0 + wave * 16 + quad * 4 + r;
        #pragma unroll
        for (int j = 0; j < 4; ++j)
            out[((size_t)b * S_ + row) * D_ + h * DH_ + j * 16 + ln] = O[j][r] * inv;
    }
}

// ---------------------------------------------------------------------------
extern "C" void kernel_launch(void* const* d_in, const int* in_sizes, int n_in,
                              void* d_out, int out_size, void* d_ws, size_t ws_size,
                              hipStream_t stream) {
    const float* x  = (const float*)d_in[0];
    const float* Wq = (const float*)d_in[1];
    const float* bq = (const float*)d_in[2];
    const float* Wk = (const float*)d_in[3];
    const float* bk = (const float*)d_in[4];
    const float* Wv = (const float*)d_in[5];
    const float* bv = (const float*)d_in[6];
    float* out = (float*)d_out;

    const size_t nmd = (size_t)M_ * D_;   // 4M
    const size_t ndd = (size_t)D_ * D_;   // 1M
    half_t* xh = (half_t*)d_ws;           // 4M halves
    half_t* Wt = xh + nmd;                // 3M halves
    half_t* Qh = Wt + 3 * ndd;            // 4M
    half_t* Kh = Qh + nmd;                // 4M
    half_t* Vh = Kh + nmd;                // 4M
    half_t* Vtw = Vh + nmd;               // 4M  (total 23M halves = 46 MB)

    convert_x_k<<<nmd / (256 * 8), 256, 0, stream>>>(x, xh);
    transW_k<<<dim3(512, 3), 256, 0, stream>>>(Wq, Wk, Wv, Wt);
    qkv_gemm_f16<<<dim3(D_ / 128, M_ / 128, 3), 256, 0, stream>>>(
        xh, Wt, bq, bk, bv, Qh, Kh, Vh);
    transV_k<<<2048, 256, 0, stream>>>(Vh, Vtw);
    attn_f16<<<dim3(S_ / 64, B_ * H_), 256, 0, stream>>>(Qh, Kh, Vtw, out);
}

// Round 4
// 209.070 us; speedup vs baseline: 5.5702x; 1.1090x over previous
//
#include <hip/hip_runtime.h>
#include <math.h>

#define B_  2
#define S_  2048
#define D_  1024
#define H_  16
#define DH_ 64
#define M_  (B_ * S_)   // 4096

typedef _Float16 half_t;
typedef __attribute__((ext_vector_type(8))) _Float16 h8;
typedef __attribute__((ext_vector_type(4))) _Float16 h4;
typedef __attribute__((ext_vector_type(4))) float   f32x4;

// async global->LDS, 16 B per lane.  LDS dest must be wave-uniform base +
// lane*16 (m104/m108) — our staging layouts are exactly lane-contiguous.
__device__ __forceinline__ void gll16(const half_t* g, half_t* l) {
    __builtin_amdgcn_global_load_lds(
        (__attribute__((address_space(1))) const void*)g,
        (__attribute__((address_space(3))) void*)l, 16, 0, 0);
}

// ---------------------------------------------------------------------------
// Prepass A: x fp32 -> fp16
// ---------------------------------------------------------------------------
__global__ __launch_bounds__(256) void convert_x_k(
    const float* __restrict__ x, half_t* __restrict__ xh)
{
    const size_t i = ((size_t)blockIdx.x * 256 + threadIdx.x) * 8;
    const float4 a = *(const float4*)(x + i);
    const float4 b = *(const float4*)(x + i + 4);
    h8 o;
    o[0] = (half_t)a.x; o[1] = (half_t)a.y; o[2] = (half_t)a.z; o[3] = (half_t)a.w;
    o[4] = (half_t)b.x; o[5] = (half_t)b.y; o[6] = (half_t)b.z; o[7] = (half_t)b.w;
    *(h8*)(xh + i) = o;
}

// ---------------------------------------------------------------------------
// Prepass B: W [k][n] fp32 -> Wt [n][k] fp16 (3 matrices)
// ---------------------------------------------------------------------------
__global__ __launch_bounds__(256) void transW_k(
    const float* __restrict__ Wq, const float* __restrict__ Wk,
    const float* __restrict__ Wv, half_t* __restrict__ Wt)
{
    const int which = blockIdx.y;
    const float* __restrict__ W = (which == 0) ? Wq : (which == 1) ? Wk : Wv;
    half_t* __restrict__ T = Wt + (size_t)which * D_ * D_;
    const int gw   = blockIdx.x * 4 + (threadIdx.x >> 6);   // 0..2047
    const int lane = threadIdx.x & 63;
    const int n    = (gw & 15) * 64 + lane;
    const int k0   = (gw >> 4) * 8;
    h8 o;
    #pragma unroll
    for (int t = 0; t < 8; ++t) o[t] = (half_t)W[(size_t)(k0 + t) * D_ + n];
    *(h8*)(T + (size_t)n * D_ + k0) = o;
}

// ---------------------------------------------------------------------------
// Prepass C: V [b][s][h*64+d] fp16 -> Vt [bh][d][s] fp16
// ---------------------------------------------------------------------------
__global__ __launch_bounds__(256) void transV_k(
    const half_t* __restrict__ V, half_t* __restrict__ Vt)
{
    const int gw   = blockIdx.x * 4 + (threadIdx.x >> 6);   // 0..8191
    const int lane = threadIdx.x & 63;                      // d
    const int bh   = gw >> 8;
    const int s0   = (gw & 255) * 8;
    const int b    = bh >> 4, h = bh & 15;
    h8 o;
    #pragma unroll
    for (int t = 0; t < 8; ++t)
        o[t] = V[((size_t)b * S_ + s0 + t) * D_ + h * DH_ + lane];
    *(h8*)(Vt + ((size_t)bh * DH_ + lane) * S_ + s0) = o;
}

// ---------------------------------------------------------------------------
// Kernel 1: fused QKV projection, m97 structure.
// One grid over concatenated n (0..3071); which = n0>>10.  128x128 tile,
// BK=32, UNPADDED LDS (stride 32 halves) -> global_load_lds width=16 with
// lane-contiguous layout.  Frag-read banks: dword = row*16 + quad*4+j;
// row parity alternates the 16-bank halves -> conflict-free without padding.
// ---------------------------------------------------------------------------
__global__ __launch_bounds__(256) void qkv_gemm_f16(
    const half_t* __restrict__ xh, const half_t* __restrict__ Wt,
    const float* __restrict__ bq, const float* __restrict__ bk,
    const float* __restrict__ bv,
    half_t* __restrict__ Qo, half_t* __restrict__ Ko, half_t* __restrict__ Vo)
{
    const int n0g   = blockIdx.x * 128;        // 0..2943
    const int which = n0g >> 10;
    const int n0    = n0g & 1023;
    const int m0    = blockIdx.y * 128;
    const half_t* __restrict__ Wp  = Wt + (size_t)which * D_ * D_;
    const float* __restrict__ bias = (which == 0) ? bq : (which == 1) ? bk : bv;
    half_t* __restrict__ out       = (which == 0) ? Qo : (which == 1) ? Ko : Vo;

    const int tid = threadIdx.x, lane = tid & 63, wave = tid >> 6;
    const int wm = (wave >> 1) * 64, wn = (wave & 1) * 64;
    const int ln = lane & 15, quad = lane >> 4;

    __shared__ __align__(16) half_t As[128][32];   // unpadded, lane-contiguous
    __shared__ __align__(16) half_t Bs[128][32];

    f32x4 acc[4][4];
    #pragma unroll
    for (int i = 0; i < 4; ++i)
        #pragma unroll
        for (int j = 0; j < 4; ++j) acc[i][j] = (f32x4){0.f, 0.f, 0.f, 0.f};

    for (int k0 = 0; k0 < D_; k0 += 32) {
        __syncthreads();                 // previous tile fully consumed
        #pragma unroll
        for (int l = 0; l < 2; ++l) {
            const int c = tid + l * 256;             // 16B-chunk index 0..511
            const int r = c >> 2, c8 = c & 3;        // 4 chunks per 32-half row
            gll16(xh + (size_t)(m0 + r) * D_ + k0 + c8 * 8, &As[r][c8 * 8]);
            gll16(Wp + (size_t)(n0 + r) * D_ + k0 + c8 * 8, &Bs[r][c8 * 8]);
        }
        __syncthreads();                 // async loads drained (vmcnt)

        h8 af[4], bf[4];
        #pragma unroll
        for (int i = 0; i < 4; ++i) af[i] = *(const h8*)&As[wm + i * 16 + ln][quad * 8];
        #pragma unroll
        for (int j = 0; j < 4; ++j) bf[j] = *(const h8*)&Bs[wn + j * 16 + ln][quad * 8];
        #pragma unroll
        for (int i = 0; i < 4; ++i)
            #pragma unroll
            for (int j = 0; j < 4; ++j)
                acc[i][j] = __builtin_amdgcn_mfma_f32_16x16x32_f16(
                    af[i], bf[j], acc[i][j], 0, 0, 0);
    }

    // Epilogue: bias (+ exact GELU for Q).  C/D: col=ln, row=quad*4+r.
    #pragma unroll
    for (int j = 0; j < 4; ++j) {
        const int col = n0 + wn + j * 16 + ln;
        const float bb = bias[col];
        #pragma unroll
        for (int i = 0; i < 4; ++i) {
            #pragma unroll
            for (int r = 0; r < 4; ++r) {
                const int row = m0 + wm + i * 16 + quad * 4 + r;
                float t = acc[i][j][r] + bb;
                if (which == 0) t = 0.5f * t * (1.0f + erff(t * 0.70710678118654752f));
                out[(size_t)row * D_ + col] = (half_t)t;
            }
        }
    }
}

// ---------------------------------------------------------------------------
// Kernel 2: flash attention, swapped-operand QK^T.
// S^T = K Q^T: A = K rows, B = Q.  C-layout => lane (quad,ln) holds 16 keys
// (16j+4quad+r) of the SINGLE q-row wave*16+ln: row-max is 15 in-register
// v_max + 2 xor-shuffles; p stays in-lane for exp; P written as 4 aligned
// ds_write_b64 into a bank-even layout (stride 36 dwords).  l via ones-MFMA.
// Q LDS is reused as the P buffer (each wave's P band == its Q band; after
// the initial sync only the owning wave touches it).  LDS = 27.6 KB.
// ---------------------------------------------------------------------------
__global__ __launch_bounds__(256) void attn_f16(
    const half_t* __restrict__ Q, const half_t* __restrict__ K,
    const half_t* __restrict__ Vt, float* __restrict__ out)
{
    const int tid  = threadIdx.x;
    const int lane = tid & 63;
    const int wave = tid >> 6;
    const int ln   = lane & 15;
    const int quad = lane >> 4;
    const int bh   = blockIdx.y;
    const int b    = bh >> 4;
    const int h    = bh & 15;
    const int q0   = blockIdx.x * 64;

    const half_t* __restrict__ Qb  = Q  + (size_t)b * S_ * D_ + h * DH_;
    const half_t* __restrict__ Kb  = K  + (size_t)b * S_ * D_ + h * DH_;
    const half_t* __restrict__ Vtb = Vt + (size_t)bh * DH_ * S_;

    __shared__ __align__(16) half_t Ks[64][72];    // [key][dim]
    __shared__ __align__(16) half_t Vs[64][72];    // [dim][key]
    __shared__ __align__(16) half_t QPs[64][72];   // Q tile, then P bands

    // ---- load Q tile, hoist Q B-fragments (each wave reads only its band) ----
    #pragma unroll
    for (int l = 0; l < 2; ++l) {
        const int c = tid + l * 256;
        const int r = c >> 3, k8 = c & 7;
        *(h8*)&QPs[r][k8 * 8] = *(const h8*)(Qb + (size_t)(q0 + r) * D_ + k8 * 8);
    }
    __syncthreads();
    const h8 qb0 = *(const h8*)&QPs[wave * 16 + ln][quad * 8];
    const h8 qb1 = *(const h8*)&QPs[wave * 16 + ln][32 + quad * 8];

    h8 ones8;
    #pragma unroll
    for (int t = 0; t < 8; ++t) ones8[t] = (half_t)1.0f;

    f32x4 O[4];
    #pragma unroll
    for (int j = 0; j < 4; ++j) O[j] = (f32x4){0.f, 0.f, 0.f, 0.f};
    f32x4 l5 = (f32x4){0.f, 0.f, 0.f, 0.f};
    float m_i = -INFINITY;                 // this lane's q-row = wave*16+ln

    for (int k0 = 0; k0 < S_; k0 += 64) {
        // ---- stage K [key][dim], V [dim][key] (padded stride, VGPR path) ----
        h8 kr[2], vr[2];
        #pragma unroll
        for (int l = 0; l < 2; ++l) {
            const int c = tid + l * 256;
            const int r = c >> 3, k8 = c & 7;
            kr[l] = *(const h8*)(Kb  + (size_t)(k0 + r) * D_ + k8 * 8);
            vr[l] = *(const h8*)(Vtb + (size_t)r * S_ + k0 + k8 * 8);
        }
        __syncthreads();
        #pragma unroll
        for (int l = 0; l < 2; ++l) {
            const int c = tid + l * 256;
            const int r = c >> 3, k8 = c & 7;
            *(h8*)&Ks[r][k8 * 8] = kr[l];
            *(h8*)&Vs[r][k8 * 8] = vr[l];
        }
        __syncthreads();

        // ---- S^T = K Q^T : lane gets keys 16j+4quad+r of q-row wave*16+ln ----
        f32x4 s[4];
        #pragma unroll
        for (int j = 0; j < 4; ++j) {
            const h8 ka0 = *(const h8*)&Ks[j * 16 + ln][quad * 8];
            const h8 ka1 = *(const h8*)&Ks[j * 16 + ln][32 + quad * 8];
            f32x4 t = (f32x4){0.f, 0.f, 0.f, 0.f};
            t = __builtin_amdgcn_mfma_f32_16x16x32_f16(ka0, qb0, t, 0, 0, 0);
            t = __builtin_amdgcn_mfma_f32_16x16x32_f16(ka1, qb1, t, 0, 0, 0);
            s[j] = t;
        }

        // ---- softmax: in-register max + 2 shuffles (4 lanes share a row) ----
        float mx = s[0][0];
        #pragma unroll
        for (int j = 0; j < 4; ++j)
            #pragma unroll
            for (int r = 0; r < 4; ++r) mx = fmaxf(mx, s[j][r]);
        mx = fmaxf(mx, __shfl_xor(mx, 16, 64));
        mx = fmaxf(mx, __shfl_xor(mx, 32, 64));
        const float mnew  = fmaxf(m_i, mx);
        const float alpha = __expf(m_i - mnew);
        m_i = mnew;

        // p = exp(s - m), packed h4, one aligned b64 write per j
        #pragma unroll
        for (int j = 0; j < 4; ++j) {
            h4 pv;
            #pragma unroll
            for (int r = 0; r < 4; ++r) pv[r] = (half_t)__expf(s[j][r] - mnew);
            *(h4*)&QPs[wave * 16 + ln][j * 16 + quad * 4] = pv;
        }

        // alpha for O/l rows quad*4+r lives in lane (quad=0, ln=quad*4+r)
        float ar[4];
        #pragma unroll
        for (int r = 0; r < 4; ++r) ar[r] = __shfl(alpha, quad * 4 + r, 64);
        #pragma unroll
        for (int r = 0; r < 4; ++r) {
            l5[r] *= ar[r];
            #pragma unroll
            for (int j = 0; j < 4; ++j) O[j][r] *= ar[r];
        }

        // ---- O += P V, l += P 1 ----
        const h8 pa0 = *(const h8*)&QPs[wave * 16 + ln][quad * 8];
        const h8 pa1 = *(const h8*)&QPs[wave * 16 + ln][32 + quad * 8];
        #pragma unroll
        for (int j = 0; j < 4; ++j) {
            const h8 vb0 = *(const h8*)&Vs[j * 16 + ln][quad * 8];
            const h8 vb1 = *(const h8*)&Vs[j * 16 + ln][32 + quad * 8];
            O[j] = __builtin_amdgcn_mfma_f32_16x16x32_f16(pa0, vb0, O[j], 0, 0, 0);
            O[j] = __builtin_amdgcn_mfma_f32_16x16x32_f16(pa1, vb1, O[j], 0, 0, 0);
        }
        l5 = __builtin_amdgcn_mfma_f32_16x16x32_f16(pa0, ones8, l5, 0, 0, 0);
        l5 = __builtin_amdgcn_mfma_f32_16x16x32_f16(pa1, ones8, l5, 0, 0, 0);
    }

    // ---- epilogue: normalize, store fp32 ----
    #pragma unroll
    for (int r = 0; r < 4; ++r) {
        const float inv = 1.0f / l5[r];
        const int row = q0 + wave * 16 + quad * 4 + r;
        #pragma unroll
        for (int j = 0; j < 4; ++j)
            out[((size_t)b * S_ + row) * D_ + h * DH_ + j * 16 + ln] = O[j][r] * inv;
    }
}

// ---------------------------------------------------------------------------
extern "C" void kernel_launch(void* const* d_in, const int* in_sizes, int n_in,
                              void* d_out, int out_size, void* d_ws, size_t ws_size,
                              hipStream_t stream) {
    const float* x  = (const float*)d_in[0];
    const float* Wq = (const float*)d_in[1];
    const float* bq = (const float*)d_in[2];
    const float* Wk = (const float*)d_in[3];
    const float* bk = (const float*)d_in[4];
    const float* Wv = (const float*)d_in[5];
    const float* bv = (const float*)d_in[6];
    float* out = (float*)d_out;

    const size_t nmd = (size_t)M_ * D_;   // 4M
    const size_t ndd = (size_t)D_ * D_;   // 1M
    half_t* xh  = (half_t*)d_ws;          // 4M halves
    half_t* Wt  = xh + nmd;               // 3M
    half_t* Qh  = Wt + 3 * ndd;           // 4M
    half_t* Kh  = Qh + nmd;               // 4M
    half_t* Vh  = Kh + nmd;               // 4M
    half_t* Vtw = Vh + nmd;               // 4M  (46 MB total)

    convert_x_k<<<nmd / (256 * 8), 256, 0, stream>>>(x, xh);
    transW_k<<<dim3(512, 3), 256, 0, stream>>>(Wq, Wk, Wv, Wt);
    qkv_gemm_f16<<<dim3(3 * D_ / 128, M_ / 128), 256, 0, stream>>>(
        xh, Wt, bq, bk, bv, Qh, Kh, Vh);
    transV_k<<<2048, 256, 0, stream>>>(Vh, Vtw);
    attn_f16<<<dim3(S_ / 64, B_ * H_), 256, 0, stream>>>(Qh, Kh, Vtw, out);
}

// Round 5
// 197.882 us; speedup vs baseline: 5.8851x; 1.0565x over previous
//
#include <hip/hip_runtime.h>
#include <math.h>

#define B_  2
#define S_  2048
#define D_  1024
#define H_  16
#define DH_ 64
#define M_  (B_ * S_)   // 4096

typedef _Float16 half_t;
typedef __attribute__((ext_vector_type(8))) _Float16 h8;
typedef __attribute__((ext_vector_type(4))) _Float16 h4;
typedef __attribute__((ext_vector_type(4))) float   f32x4;

#define LOG2E 1.44269504088896f

// async global->LDS, 16 B per lane (lane-contiguous dest required, m104/m108)
__device__ __forceinline__ void gll16(const half_t* g, half_t* l) {
    __builtin_amdgcn_global_load_lds(
        (__attribute__((address_space(1))) const void*)g,
        (__attribute__((address_space(3))) void*)l, 16, 0, 0);
}

// ---------------------------------------------------------------------------
// Prepass A: x fp32 -> fp16
// ---------------------------------------------------------------------------
__global__ __launch_bounds__(256) void convert_x_k(
    const float* __restrict__ x, half_t* __restrict__ xh)
{
    const size_t i = ((size_t)blockIdx.x * 256 + threadIdx.x) * 8;
    const float4 a = *(const float4*)(x + i);
    const float4 b = *(const float4*)(x + i + 4);
    h8 o;
    o[0] = (half_t)a.x; o[1] = (half_t)a.y; o[2] = (half_t)a.z; o[3] = (half_t)a.w;
    o[4] = (half_t)b.x; o[5] = (half_t)b.y; o[6] = (half_t)b.z; o[7] = (half_t)b.w;
    *(h8*)(xh + i) = o;
}

// ---------------------------------------------------------------------------
// Prepass B: W [k][n] fp32 -> Wt [n][k] fp16 (3 matrices)
// ---------------------------------------------------------------------------
__global__ __launch_bounds__(256) void transW_k(
    const float* __restrict__ Wq, const float* __restrict__ Wk,
    const float* __restrict__ Wv, half_t* __restrict__ Wt)
{
    const int which = blockIdx.y;
    const float* __restrict__ W = (which == 0) ? Wq : (which == 1) ? Wk : Wv;
    half_t* __restrict__ T = Wt + (size_t)which * D_ * D_;
    const int gw   = blockIdx.x * 4 + (threadIdx.x >> 6);   // 0..2047
    const int lane = threadIdx.x & 63;
    const int n    = (gw & 15) * 64 + lane;
    const int k0   = (gw >> 4) * 8;
    h8 o;
    #pragma unroll
    for (int t = 0; t < 8; ++t) o[t] = (half_t)W[(size_t)(k0 + t) * D_ + n];
    *(h8*)(T + (size_t)n * D_ + k0) = o;
}

// ---------------------------------------------------------------------------
// Prepass C: V [b][s][h*64+d] fp16 -> Vt [bh][d][s] fp16
// ---------------------------------------------------------------------------
__global__ __launch_bounds__(256) void transV_k(
    const half_t* __restrict__ V, half_t* __restrict__ Vt)
{
    const int gw   = blockIdx.x * 4 + (threadIdx.x >> 6);   // 0..8191
    const int lane = threadIdx.x & 63;                      // d
    const int bh   = gw >> 8;
    const int s0   = (gw & 255) * 8;
    const int b    = bh >> 4, h = bh & 15;
    h8 o;
    #pragma unroll
    for (int t = 0; t < 8; ++t)
        o[t] = V[((size_t)b * S_ + s0 + t) * D_ + h * DH_ + lane];
    *(h8*)(Vt + ((size_t)bh * DH_ + lane) * S_ + s0) = o;
}

// ---------------------------------------------------------------------------
// Kernel 1: fused QKV projection, m97 structure (BK=32, global_load_lds).
// GELU: tanh approximation via exp2+rcp (err ~3e-3, threshold 8.8e-2).
// Q output is pre-scaled by log2(e) so attention can use 2^x directly.
// ---------------------------------------------------------------------------
__global__ __launch_bounds__(256) void qkv_gemm_f16(
    const half_t* __restrict__ xh, const half_t* __restrict__ Wt,
    const float* __restrict__ bq, const float* __restrict__ bk,
    const float* __restrict__ bv,
    half_t* __restrict__ Qo, half_t* __restrict__ Ko, half_t* __restrict__ Vo)
{
    const int n0g   = blockIdx.x * 128;        // 0..2943
    const int which = n0g >> 10;
    const int n0    = n0g & 1023;
    const int m0    = blockIdx.y * 128;
    const half_t* __restrict__ Wp  = Wt + (size_t)which * D_ * D_;
    const float* __restrict__ bias = (which == 0) ? bq : (which == 1) ? bk : bv;
    half_t* __restrict__ out       = (which == 0) ? Qo : (which == 1) ? Ko : Vo;

    const int tid = threadIdx.x, lane = tid & 63, wave = tid >> 6;
    const int wm = (wave >> 1) * 64, wn = (wave & 1) * 64;
    const int ln = lane & 15, quad = lane >> 4;

    __shared__ __align__(16) half_t As[128][32];   // unpadded, lane-contiguous
    __shared__ __align__(16) half_t Bs[128][32];

    f32x4 acc[4][4];
    #pragma unroll
    for (int i = 0; i < 4; ++i)
        #pragma unroll
        for (int j = 0; j < 4; ++j) acc[i][j] = (f32x4){0.f, 0.f, 0.f, 0.f};

    for (int k0 = 0; k0 < D_; k0 += 32) {
        __syncthreads();
        #pragma unroll
        for (int l = 0; l < 2; ++l) {
            const int c = tid + l * 256;             // 16B-chunk 0..511
            const int r = c >> 2, c8 = c & 3;
            gll16(xh + (size_t)(m0 + r) * D_ + k0 + c8 * 8, &As[r][c8 * 8]);
            gll16(Wp + (size_t)(n0 + r) * D_ + k0 + c8 * 8, &Bs[r][c8 * 8]);
        }
        __syncthreads();

        h8 af[4], bf[4];
        #pragma unroll
        for (int i = 0; i < 4; ++i) af[i] = *(const h8*)&As[wm + i * 16 + ln][quad * 8];
        #pragma unroll
        for (int j = 0; j < 4; ++j) bf[j] = *(const h8*)&Bs[wn + j * 16 + ln][quad * 8];
        #pragma unroll
        for (int i = 0; i < 4; ++i)
            #pragma unroll
            for (int j = 0; j < 4; ++j)
                acc[i][j] = __builtin_amdgcn_mfma_f32_16x16x32_f16(
                    af[i], bf[j], acc[i][j], 0, 0, 0);
    }

    // Epilogue: bias (+ tanh-GELU * log2e for Q).  C/D: col=ln, row=quad*4+r.
    #pragma unroll
    for (int j = 0; j < 4; ++j) {
        const int col = n0 + wn + j * 16 + ln;
        const float bb = bias[col];
        #pragma unroll
        for (int i = 0; i < 4; ++i) {
            #pragma unroll
            for (int r = 0; r < 4; ++r) {
                const int row = m0 + wm + i * 16 + quad * 4 + r;
                float t = acc[i][j][r] + bb;
                if (which == 0) {
                    // gelu_tanh(t) = t * sigmoid(2u), u = 0.79788456*(t+0.044715 t^3)
                    const float u = t * fmaf(t * t, 0.0356774081f, 0.7978845608f);
                    const float e = __builtin_amdgcn_exp2f(u * -2.88539008178f);
                    t = t * __builtin_amdgcn_rcpf(1.0f + e) * LOG2E;
                }
                out[(size_t)row * D_ + col] = (half_t)t;
            }
        }
    }
}

// ---------------------------------------------------------------------------
// Kernel 2: flash attention.  S^T = K Q^T (lane owns one q-row, 16 keys).
// K/V staged by global_load_lds into unpadded 64x64 tiles with XOR chunk
// swizzle slot = r*8 + (c ^ (r&7)): lane-contiguous for DMA, frag reads hit
// 8 disjoint bank windows (2-way max = free).  Logits arrive pre-scaled by
// log2e -> p = 2^(s-m) via v_exp_f32.  O/l rescale skipped unless the wave's
// running max actually changed (ballot-uniform branch; ~5 of 32 tiles).
// LDS = 8 + 8 + 9.2 = 25.2 KB.
// ---------------------------------------------------------------------------
__global__ __launch_bounds__(256) void attn_f16(
    const half_t* __restrict__ Q, const half_t* __restrict__ K,
    const half_t* __restrict__ Vt, float* __restrict__ out)
{
    const int tid  = threadIdx.x;
    const int lane = tid & 63;
    const int wave = tid >> 6;
    const int ln   = lane & 15;
    const int quad = lane >> 4;
    const int bh   = blockIdx.y;
    const int b    = bh >> 4;
    const int h    = bh & 15;
    const int q0   = blockIdx.x * 64;

    const half_t* __restrict__ Qb  = Q  + (size_t)b * S_ * D_ + h * DH_;
    const half_t* __restrict__ Kb  = K  + (size_t)b * S_ * D_ + h * DH_;
    const half_t* __restrict__ Vtb = Vt + (size_t)bh * DH_ * S_;

    __shared__ __align__(16) half_t Ks[64 * 64];   // swizzled slots
    __shared__ __align__(16) half_t Vs[64 * 64];   // swizzled slots
    __shared__ __align__(16) half_t QPs[64][72];   // Q tile, then P bands

    // ---- load Q tile, hoist Q B-fragments ----
    #pragma unroll
    for (int l = 0; l < 2; ++l) {
        const int c = tid + l * 256;
        const int r = c >> 3, k8 = c & 7;
        *(h8*)&QPs[r][k8 * 8] = *(const h8*)(Qb + (size_t)(q0 + r) * D_ + k8 * 8);
    }
    __syncthreads();
    const h8 qb0 = *(const h8*)&QPs[wave * 16 + ln][quad * 8];
    const h8 qb1 = *(const h8*)&QPs[wave * 16 + ln][32 + quad * 8];

    h8 ones8;
    #pragma unroll
    for (int t = 0; t < 8; ++t) ones8[t] = (half_t)1.0f;

    f32x4 O[4];
    #pragma unroll
    for (int j = 0; j < 4; ++j) O[j] = (f32x4){0.f, 0.f, 0.f, 0.f};
    f32x4 l5 = (f32x4){0.f, 0.f, 0.f, 0.f};
    float m_i = -INFINITY;                 // this lane's q-row = wave*16+ln

    for (int k0 = 0; k0 < S_; k0 += 64) {
        // ---- stage K and V via async DMA, swizzled ----
        __syncthreads();                   // previous tile fully consumed
        #pragma unroll
        for (int l = 0; l < 2; ++l) {
            const int c = tid + l * 256;                 // slot 0..511
            const int r = c >> 3, c0 = c & 7;
            const int cs = c0 ^ (r & 7);                 // logical chunk
            gll16(Kb  + (size_t)(k0 + r) * D_ + cs * 8, &Ks[c * 8]);
            gll16(Vtb + (size_t)r * S_ + k0 + cs * 8,   &Vs[c * 8]);
        }
        __syncthreads();                   // DMA drained (vmcnt at barrier)

        // ---- S^T = K Q^T : lane gets keys 16j+4quad+r of q-row wave*16+ln ----
        f32x4 s[4];
        #pragma unroll
        for (int j = 0; j < 4; ++j) {
            const int rK = j * 16 + ln;
            const h8 ka0 = *(const h8*)&Ks[rK * 64 + ((quad)     ^ (rK & 7)) * 8];
            const h8 ka1 = *(const h8*)&Ks[rK * 64 + ((quad + 4) ^ (rK & 7)) * 8];
            f32x4 t = (f32x4){0.f, 0.f, 0.f, 0.f};
            t = __builtin_amdgcn_mfma_f32_16x16x32_f16(ka0, qb0, t, 0, 0, 0);
            t = __builtin_amdgcn_mfma_f32_16x16x32_f16(ka1, qb1, t, 0, 0, 0);
            s[j] = t;
        }

        // ---- online softmax (log2-domain): conditional rescale ----
        float mx = fmaxf(fmaxf(fmaxf(s[0][0], s[0][1]), fmaxf(s[0][2], s[0][3])),
                         fmaxf(fmaxf(s[1][0], s[1][1]), fmaxf(s[1][2], s[1][3])));
        mx = fmaxf(mx, fmaxf(fmaxf(fmaxf(s[2][0], s[2][1]), fmaxf(s[2][2], s[2][3])),
                             fmaxf(fmaxf(s[3][0], s[3][1]), fmaxf(s[3][2], s[3][3]))));
        mx = fmaxf(mx, __shfl_xor(mx, 16, 64));
        mx = fmaxf(mx, __shfl_xor(mx, 32, 64));

        if (__ballot(mx > m_i)) {          // wave-uniform: any row's max moved
            const float mnew  = fmaxf(m_i, mx);
            const float alpha = __builtin_amdgcn_exp2f(m_i - mnew);
            m_i = mnew;
            float ar[4];
            #pragma unroll
            for (int r = 0; r < 4; ++r) ar[r] = __shfl(alpha, quad * 4 + r, 64);
            #pragma unroll
            for (int r = 0; r < 4; ++r) {
                l5[r] *= ar[r];
                #pragma unroll
                for (int j = 0; j < 4; ++j) O[j][r] *= ar[r];
            }
        }

        // p = 2^(s - m), packed h4, one aligned b64 write per j
        #pragma unroll
        for (int j = 0; j < 4; ++j) {
            h4 pv;
            #pragma unroll
            for (int r = 0; r < 4; ++r)
                pv[r] = (half_t)__builtin_amdgcn_exp2f(s[j][r] - m_i);
            *(h4*)&QPs[wave * 16 + ln][j * 16 + quad * 4] = pv;
        }

        // ---- O += P V, l += P 1 ----
        const h8 pa0 = *(const h8*)&QPs[wave * 16 + ln][quad * 8];
        const h8 pa1 = *(const h8*)&QPs[wave * 16 + ln][32 + quad * 8];
        #pragma unroll
        for (int j = 0; j < 4; ++j) {
            const int rV = j * 16 + ln;
            const h8 vb0 = *(const h8*)&Vs[rV * 64 + ((quad)     ^ (rV & 7)) * 8];
            const h8 vb1 = *(const h8*)&Vs[rV * 64 + ((quad + 4) ^ (rV & 7)) * 8];
            O[j] = __builtin_amdgcn_mfma_f32_16x16x32_f16(pa0, vb0, O[j], 0, 0, 0);
            O[j] = __builtin_amdgcn_mfma_f32_16x16x32_f16(pa1, vb1, O[j], 0, 0, 0);
        }
        l5 = __builtin_amdgcn_mfma_f32_16x16x32_f16(pa0, ones8, l5, 0, 0, 0);
        l5 = __builtin_amdgcn_mfma_f32_16x16x32_f16(pa1, ones8, l5, 0, 0, 0);
    }

    // ---- epilogue: normalize, store fp32 ----
    #pragma unroll
    for (int r = 0; r < 4; ++r) {
        const float inv = 1.0f / l5[r];
        const int row = q0 + wave * 16 + quad * 4 + r;
        #pragma unroll
        for (int j = 0; j < 4; ++j)
            out[((size_t)b * S_ + row) * D_ + h * DH_ + j * 16 + ln] = O[j][r] * inv;
    }
}

// ---------------------------------------------------------------------------
extern "C" void kernel_launch(void* const* d_in, const int* in_sizes, int n_in,
                              void* d_out, int out_size, void* d_ws, size_t ws_size,
                              hipStream_t stream) {
    const float* x  = (const float*)d_in[0];
    const float* Wq = (const float*)d_in[1];
    const float* bq = (const float*)d_in[2];
    const float* Wk = (const float*)d_in[3];
    const float* bk = (const float*)d_in[4];
    const float* Wv = (const float*)d_in[5];
    const float* bv = (const float*)d_in[6];
    float* out = (float*)d_out;

    const size_t nmd = (size_t)M_ * D_;   // 4M
    const size_t ndd = (size_t)D_ * D_;   // 1M
    half_t* xh  = (half_t*)d_ws;          // 4M halves
    half_t* Wt  = xh + nmd;               // 3M
    half_t* Qh  = Wt + 3 * ndd;           // 4M
    half_t* Kh  = Qh + nmd;               // 4M
    half_t* Vh  = Kh + nmd;               // 4M
    half_t* Vtw = Vh + nmd;               // 4M  (46 MB total)

    convert_x_k<<<nmd / (256 * 8), 256, 0, stream>>>(x, xh);
    transW_k<<<dim3(512, 3), 256, 0, stream>>>(Wq, Wk, Wv, Wt);
    qkv_gemm_f16<<<dim3(3 * D_ / 128, M_ / 128), 256, 0, stream>>>(
        xh, Wt, bq, bk, bv, Qh, Kh, Vh);
    transV_k<<<2048, 256, 0, stream>>>(Vh, Vtw);
    attn_f16<<<dim3(S_ / 64, B_ * H_), 256, 0, stream>>>(Qh, Kh, Vtw, out);
}

// Round 6
// 195.969 us; speedup vs baseline: 5.9425x; 1.0098x over previous
//
#include <hip/hip_runtime.h>
#include <math.h>

#define B_  2
#define S_  2048
#define D_  1024
#define H_  16
#define DH_ 64
#define M_  (B_ * S_)   // 4096

typedef _Float16 half_t;
typedef __attribute__((ext_vector_type(8))) _Float16 h8;
typedef __attribute__((ext_vector_type(4))) _Float16 h4;
typedef __attribute__((ext_vector_type(4))) float   f32x4;

#define LOG2E 1.44269504088896f

// async global->LDS, 16 B per lane (lane-contiguous dest, m104/m108)
__device__ __forceinline__ void gll16(const half_t* g, half_t* l) {
    __builtin_amdgcn_global_load_lds(
        (__attribute__((address_space(1))) const void*)g,
        (__attribute__((address_space(3))) void*)l, 16, 0, 0);
}

// ---------------------------------------------------------------------------
// Prepass (fused): blocks 0..2047 convert x fp32->fp16; blocks 2048..3583
// transpose W [k][n] fp32 -> Wt [n][k] fp16 (3 matrices).
// ---------------------------------------------------------------------------
__global__ __launch_bounds__(256) void prep_k(
    const float* __restrict__ x, half_t* __restrict__ xh,
    const float* __restrict__ Wq, const float* __restrict__ Wk,
    const float* __restrict__ Wv, half_t* __restrict__ Wt)
{
    const int bx = blockIdx.x;
    if (bx < 2048) {
        const size_t i = ((size_t)bx * 256 + threadIdx.x) * 8;
        const float4 a = *(const float4*)(x + i);
        const float4 b = *(const float4*)(x + i + 4);
        h8 o;
        o[0] = (half_t)a.x; o[1] = (half_t)a.y; o[2] = (half_t)a.z; o[3] = (half_t)a.w;
        o[4] = (half_t)b.x; o[5] = (half_t)b.y; o[6] = (half_t)b.z; o[7] = (half_t)b.w;
        *(h8*)(xh + i) = o;
    } else {
        const int gb    = bx - 2048;                 // 0..1535
        const int which = gb >> 9;                   // 512 blocks per matrix
        const float* __restrict__ W = (which == 0) ? Wq : (which == 1) ? Wk : Wv;
        half_t* __restrict__ T = Wt + (size_t)which * D_ * D_;
        const int gw   = (gb & 511) * 4 + (threadIdx.x >> 6);   // 0..2047
        const int lane = threadIdx.x & 63;
        const int n    = (gw & 15) * 64 + lane;
        const int k0   = (gw >> 4) * 8;
        h8 o;
        #pragma unroll
        for (int t = 0; t < 8; ++t) o[t] = (half_t)W[(size_t)(k0 + t) * D_ + n];
        *(h8*)(T + (size_t)n * D_ + k0) = o;
    }
}

// ---------------------------------------------------------------------------
// Kernel 1: fused QKV projection.  128x128 tile, BK=64, global_load_lds into
// XOR-chunk-swizzled unpadded LDS (slot = r*8 + (c ^ (r&7))): lane-contiguous
// for the DMA, conflict-free b128 frag reads.  32 MFMA per wave per barrier
// pair (2x the BK=32 version).  Epilogue: Q = tanh-GELU * log2e (natural
// layout), K natural, V stored PRE-TRANSPOSED as Vt[bh][d][s] via h4 stores
// (s is the C-layout reg index -> contiguous), eliminating the transV pass.
// ---------------------------------------------------------------------------
__global__ __launch_bounds__(256) void qkv_gemm_f16(
    const half_t* __restrict__ xh, const half_t* __restrict__ Wt,
    const float* __restrict__ bq, const float* __restrict__ bk,
    const float* __restrict__ bv,
    half_t* __restrict__ Qo, half_t* __restrict__ Ko, half_t* __restrict__ Vt)
{
    const int n0g   = blockIdx.x * 128;        // 0..2943
    const int which = n0g >> 10;
    const int n0    = n0g & 1023;
    const int m0    = blockIdx.y * 128;
    const half_t* __restrict__ Wp  = Wt + (size_t)which * D_ * D_;
    const float* __restrict__ bias = (which == 0) ? bq : (which == 1) ? bk : bv;

    const int tid = threadIdx.x, lane = tid & 63, wave = tid >> 6;
    const int wm = (wave >> 1) * 64, wn = (wave & 1) * 64;
    const int ln = lane & 15, quad = lane >> 4;

    __shared__ __align__(16) half_t As[128 * 64];   // swizzled slots
    __shared__ __align__(16) half_t Bs[128 * 64];

    f32x4 acc[4][4];
    #pragma unroll
    for (int i = 0; i < 4; ++i)
        #pragma unroll
        for (int j = 0; j < 4; ++j) acc[i][j] = (f32x4){0.f, 0.f, 0.f, 0.f};

    for (int k0 = 0; k0 < D_; k0 += 64) {
        __syncthreads();                  // previous tile fully consumed
        #pragma unroll
        for (int l = 0; l < 4; ++l) {
            const int c  = tid + l * 256;            // chunk slot 0..1023
            const int r  = c >> 3, c0 = c & 7;
            const int cs = c0 ^ (r & 7);             // logical 16B chunk
            gll16(xh + (size_t)(m0 + r) * D_ + k0 + cs * 8, &As[c * 8]);
            gll16(Wp + (size_t)(n0 + r) * D_ + k0 + cs * 8, &Bs[c * 8]);
        }
        __syncthreads();                  // DMA drained at barrier

        #pragma unroll
        for (int kc = 0; kc < 2; ++kc) {
            h8 af[4], bf[4];
            #pragma unroll
            for (int i = 0; i < 4; ++i) {
                const int r = wm + i * 16 + ln;
                af[i] = *(const h8*)&As[r * 64 + (((kc << 2) + quad) ^ (r & 7)) * 8];
            }
            #pragma unroll
            for (int j = 0; j < 4; ++j) {
                const int r = wn + j * 16 + ln;
                bf[j] = *(const h8*)&Bs[r * 64 + (((kc << 2) + quad) ^ (r & 7)) * 8];
            }
            #pragma unroll
            for (int i = 0; i < 4; ++i)
                #pragma unroll
                for (int j = 0; j < 4; ++j)
                    acc[i][j] = __builtin_amdgcn_mfma_f32_16x16x32_f16(
                        af[i], bf[j], acc[i][j], 0, 0, 0);
        }
    }

    // Epilogue.  C/D: col=ln, row=quad*4+r.
    if (which == 2) {
        // V -> Vt[bh][d][s], h4 stores along s (s = reg index, contiguous)
        #pragma unroll
        for (int j = 0; j < 4; ++j) {
            const int col = n0 + wn + j * 16 + ln;   // 0..1023
            const int h = col >> 6, d = col & 63;
            const float bb = bias[col];
            #pragma unroll
            for (int i = 0; i < 4; ++i) {
                const int sg = m0 + wm + i * 16 + quad * 4;   // global row
                const int b  = sg >> 11, srow = sg & 2047;
                h4 pv;
                #pragma unroll
                for (int r = 0; r < 4; ++r) pv[r] = (half_t)(acc[i][j][r] + bb);
                *(h4*)(Vt + (((size_t)(b * H_ + h) * DH_ + d) * S_ + srow)) = pv;
            }
        }
    } else {
        half_t* __restrict__ out = (which == 0) ? Qo : Ko;
        #pragma unroll
        for (int j = 0; j < 4; ++j) {
            const int col = n0 + wn + j * 16 + ln;
            const float bb = bias[col];
            #pragma unroll
            for (int i = 0; i < 4; ++i) {
                #pragma unroll
                for (int r = 0; r < 4; ++r) {
                    const int row = m0 + wm + i * 16 + quad * 4 + r;
                    float t = acc[i][j][r] + bb;
                    if (which == 0) {
                        const float u = t * fmaf(t * t, 0.0356774081f, 0.7978845608f);
                        const float e = __builtin_amdgcn_exp2f(u * -2.88539008178f);
                        t = t * __builtin_amdgcn_rcpf(1.0f + e) * LOG2E;
                    }
                    out[(size_t)row * D_ + col] = (half_t)t;
                }
            }
        }
    }
}

// ---------------------------------------------------------------------------
// Kernel 2: flash attention, 128 q-rows per block (4 waves x 32 q-rows).
// Each wave hoists TWO Q fragment pairs -> every K/V fragment read feeds 2
// MFMAs (2x arithmetic intensity on the LDS pipe vs the 64-q version).
// K/V staged by global_load_lds, XOR-swizzled.  Logits pre-scaled by log2e
// (p = 2^x).  Conditional O/l rescale (ballot-uniform).  l via ones-MFMA.
// LDS = 8 + 8 + 18 = 34 KB.
// ---------------------------------------------------------------------------
__global__ __launch_bounds__(256) void attn_f16(
    const half_t* __restrict__ Q, const half_t* __restrict__ K,
    const half_t* __restrict__ Vt, float* __restrict__ out)
{
    const int tid  = threadIdx.x;
    const int lane = tid & 63;
    const int wave = tid >> 6;
    const int ln   = lane & 15;
    const int quad = lane >> 4;
    const int bh   = blockIdx.y;
    const int b    = bh >> 4;
    const int h    = bh & 15;
    const int q0   = blockIdx.x * 128;

    const half_t* __restrict__ Qb  = Q  + (size_t)b * S_ * D_ + h * DH_;
    const half_t* __restrict__ Kb  = K  + (size_t)b * S_ * D_ + h * DH_;
    const half_t* __restrict__ Vtb = Vt + (size_t)bh * DH_ * S_;

    __shared__ __align__(16) half_t Ks[64 * 64];    // swizzled slots
    __shared__ __align__(16) half_t Vs[64 * 64];    // swizzled slots
    __shared__ __align__(16) half_t QPs[128][72];   // Q tile, then P bands

    // ---- load Q tile (128x64), hoist both Q fragment pairs ----
    #pragma unroll
    for (int l = 0; l < 4; ++l) {
        const int c = tid + l * 256;
        const int r = c >> 3, k8 = c & 7;
        *(h8*)&QPs[r][k8 * 8] = *(const h8*)(Qb + (size_t)(q0 + r) * D_ + k8 * 8);
    }
    __syncthreads();
    const h8 qa0 = *(const h8*)&QPs[wave * 32 + ln][quad * 8];
    const h8 qa1 = *(const h8*)&QPs[wave * 32 + ln][32 + quad * 8];
    const h8 qc0 = *(const h8*)&QPs[wave * 32 + 16 + ln][quad * 8];
    const h8 qc1 = *(const h8*)&QPs[wave * 32 + 16 + ln][32 + quad * 8];

    h8 ones8;
    #pragma unroll
    for (int t = 0; t < 8; ++t) ones8[t] = (half_t)1.0f;

    f32x4 Oa[4], Ob[4];
    #pragma unroll
    for (int j = 0; j < 4; ++j) {
        Oa[j] = (f32x4){0.f, 0.f, 0.f, 0.f};
        Ob[j] = (f32x4){0.f, 0.f, 0.f, 0.f};
    }
    f32x4 la = (f32x4){0.f, 0.f, 0.f, 0.f};
    f32x4 lb = (f32x4){0.f, 0.f, 0.f, 0.f};
    float m_a = -INFINITY, m_b = -INFINITY;   // rows wave*32+ln, +16+ln

    for (int k0 = 0; k0 < S_; k0 += 64) {
        // ---- stage K and V via async DMA, swizzled ----
        __syncthreads();                   // previous tile fully consumed
        #pragma unroll
        for (int l = 0; l < 2; ++l) {
            const int c  = tid + l * 256;            // slot 0..511
            const int r  = c >> 3, c0 = c & 7;
            const int cs = c0 ^ (r & 7);
            gll16(Kb  + (size_t)(k0 + r) * D_ + cs * 8, &Ks[c * 8]);
            gll16(Vtb + (size_t)r * S_ + k0 + cs * 8,   &Vs[c * 8]);
        }
        __syncthreads();                   // DMA drained

        // ---- S^T = K Q^T for both q-groups ----
        f32x4 sa[4], sb[4];
        #pragma unroll
        for (int j = 0; j < 4; ++j) {
            const int rK = j * 16 + ln;
            const h8 ka0 = *(const h8*)&Ks[rK * 64 + ((quad)     ^ (rK & 7)) * 8];
            const h8 ka1 = *(const h8*)&Ks[rK * 64 + ((quad + 4) ^ (rK & 7)) * 8];
            f32x4 t = (f32x4){0.f, 0.f, 0.f, 0.f};
            t = __builtin_amdgcn_mfma_f32_16x16x32_f16(ka0, qa0, t, 0, 0, 0);
            t = __builtin_amdgcn_mfma_f32_16x16x32_f16(ka1, qa1, t, 0, 0, 0);
            sa[j] = t;
            f32x4 u = (f32x4){0.f, 0.f, 0.f, 0.f};
            u = __builtin_amdgcn_mfma_f32_16x16x32_f16(ka0, qc0, u, 0, 0, 0);
            u = __builtin_amdgcn_mfma_f32_16x16x32_f16(ka1, qc1, u, 0, 0, 0);
            sb[j] = u;
        }

        // ---- online softmax (log2 domain), conditional rescale ----
        float mxa = sa[0][0], mxb = sb[0][0];
        #pragma unroll
        for (int j = 0; j < 4; ++j)
            #pragma unroll
            for (int r = 0; r < 4; ++r) {
                mxa = fmaxf(mxa, sa[j][r]);
                mxb = fmaxf(mxb, sb[j][r]);
            }
        mxa = fmaxf(mxa, __shfl_xor(mxa, 16, 64));
        mxa = fmaxf(mxa, __shfl_xor(mxa, 32, 64));
        mxb = fmaxf(mxb, __shfl_xor(mxb, 16, 64));
        mxb = fmaxf(mxb, __shfl_xor(mxb, 32, 64));

        if (__ballot(mxa > m_a || mxb > m_b)) {
            const float mna = fmaxf(m_a, mxa);
            const float mnb = fmaxf(m_b, mxb);
            const float ala = __builtin_amdgcn_exp2f(m_a - mna);
            const float alb = __builtin_amdgcn_exp2f(m_b - mnb);
            m_a = mna; m_b = mnb;
            float ra[4], rb[4];
            #pragma unroll
            for (int r = 0; r < 4; ++r) {
                ra[r] = __shfl(ala, quad * 4 + r, 64);
                rb[r] = __shfl(alb, quad * 4 + r, 64);
            }
            #pragma unroll
            for (int r = 0; r < 4; ++r) {
                la[r] *= ra[r]; lb[r] *= rb[r];
                #pragma unroll
                for (int j = 0; j < 4; ++j) { Oa[j][r] *= ra[r]; Ob[j][r] *= rb[r]; }
            }
        }

        // p = 2^(s - m), h4-packed b64 writes into wave-private bands
        #pragma unroll
        for (int j = 0; j < 4; ++j) {
            h4 pva, pvb;
            #pragma unroll
            for (int r = 0; r < 4; ++r) {
                pva[r] = (half_t)__builtin_amdgcn_exp2f(sa[j][r] - m_a);
                pvb[r] = (half_t)__builtin_amdgcn_exp2f(sb[j][r] - m_b);
            }
            *(h4*)&QPs[wave * 32 + ln][j * 16 + quad * 4]      = pva;
            *(h4*)&QPs[wave * 32 + 16 + ln][j * 16 + quad * 4] = pvb;
        }

        // ---- O += P V, l += P 1 (both q-groups share each V fragment) ----
        const h8 pa0 = *(const h8*)&QPs[wave * 32 + ln][quad * 8];
        const h8 pa1 = *(const h8*)&QPs[wave * 32 + ln][32 + quad * 8];
        const h8 pb0 = *(const h8*)&QPs[wave * 32 + 16 + ln][quad * 8];
        const h8 pb1 = *(const h8*)&QPs[wave * 32 + 16 + ln][32 + quad * 8];
        #pragma unroll
        for (int j = 0; j < 4; ++j) {
            const int rV = j * 16 + ln;
            const h8 vb0 = *(const h8*)&Vs[rV * 64 + ((quad)     ^ (rV & 7)) * 8];
            const h8 vb1 = *(const h8*)&Vs[rV * 64 + ((quad + 4) ^ (rV & 7)) * 8];
            Oa[j] = __builtin_amdgcn_mfma_f32_16x16x32_f16(pa0, vb0, Oa[j], 0, 0, 0);
            Oa[j] = __builtin_amdgcn_mfma_f32_16x16x32_f16(pa1, vb1, Oa[j], 0, 0, 0);
            Ob[j] = __builtin_amdgcn_mfma_f32_16x16x32_f16(pb0, vb0, Ob[j], 0, 0, 0);
            Ob[j] = __builtin_amdgcn_mfma_f32_16x16x32_f16(pb1, vb1, Ob[j], 0, 0, 0);
        }
        la = __builtin_amdgcn_mfma_f32_16x16x32_f16(pa0, ones8, la, 0, 0, 0);
        la = __builtin_amdgcn_mfma_f32_16x16x32_f16(pa1, ones8, la, 0, 0, 0);
        lb = __builtin_amdgcn_mfma_f32_16x16x32_f16(pb0, ones8, lb, 0, 0, 0);
        lb = __builtin_amdgcn_mfma_f32_16x16x32_f16(pb1, ones8, lb, 0, 0, 0);
    }

    // ---- epilogue: normalize, store fp32 ----
    #pragma unroll
    for (int r = 0; r < 4; ++r) {
        const float iva = 1.0f / la[r];
        const float ivb = 1.0f / lb[r];
        const int rowa = q0 + wave * 32 + quad * 4 + r;
        const int rowb = rowa + 16;
        #pragma unroll
        for (int j = 0; j < 4; ++j) {
            out[((size_t)b * S_ + rowa) * D_ + h * DH_ + j * 16 + ln] = Oa[j][r] * iva;
            out[((size_t)b * S_ + rowb) * D_ + h * DH_ + j * 16 + ln] = Ob[j][r] * ivb;
        }
    }
}

// ---------------------------------------------------------------------------
extern "C" void kernel_launch(void* const* d_in, const int* in_sizes, int n_in,
                              void* d_out, int out_size, void* d_ws, size_t ws_size,
                              hipStream_t stream) {
    const float* x  = (const float*)d_in[0];
    const float* Wq = (const float*)d_in[1];
    const float* bq = (const float*)d_in[2];
    const float* Wk = (const float*)d_in[3];
    const float* bk = (const float*)d_in[4];
    const float* Wv = (const float*)d_in[5];
    const float* bv = (const float*)d_in[6];
    float* out = (float*)d_out;

    const size_t nmd = (size_t)M_ * D_;   // 4M
    const size_t ndd = (size_t)D_ * D_;   // 1M
    half_t* xh  = (half_t*)d_ws;          // 4M halves
    half_t* Wt  = xh + nmd;               // 3M
    half_t* Qh  = Wt + 3 * ndd;           // 4M
    half_t* Kh  = Qh + nmd;               // 4M
    half_t* Vtw = Kh + nmd;               // 4M  (38 MB total)

    prep_k<<<2048 + 1536, 256, 0, stream>>>(x, xh, Wq, Wk, Wv, Wt);
    qkv_gemm_f16<<<dim3(3 * D_ / 128, M_ / 128), 256, 0, stream>>>(
        xh, Wt, bq, bk, bv, Qh, Kh, Vtw);
    attn_f16<<<dim3(S_ / 128, B_ * H_), 256, 0, stream>>>(Qh, Kh, Vtw, out);
}